// Round 4
// baseline (995.140 us; speedup 1.0000x reference)
//
#include <hip/hip_runtime.h>

#define FIN 1024
#define FH  512
#define BM  128
#define BN  128
#define BK  32

typedef __attribute__((ext_vector_type(8))) short short8;
typedef __attribute__((ext_vector_type(4))) float f32x4;
typedef __attribute__((address_space(1))) void gvoid;
typedef __attribute__((address_space(3))) void lvoid;

// ---- bf16 helpers (RNE) ----
static __device__ __forceinline__ unsigned short f2bf(float f) {
    unsigned u = __float_as_uint(f);
    unsigned r = (u + 0x7FFFu + ((u >> 16) & 1u)) >> 16;
    return (unsigned short)r;
}
static __device__ __forceinline__ float bf2f(unsigned short h) {
    return __uint_as_float((unsigned)h << 16);
}

// ---------------- degree: deg[t] = #edges into t ----------------
__global__ void k_deg(const int* __restrict__ tgt, int E, int* __restrict__ deg) {
    int e = blockIdx.x * blockDim.x + threadIdx.x;
    if (e < E) atomicAdd(&deg[tgt[e]], 1);
}

// ---------------- per-node: dinv_sqrt, generator mask, flag init ----------------
__global__ void k_node(const float* __restrict__ x, const int* __restrict__ deg,
                       float* __restrict__ dinv, int* __restrict__ mask,
                       int* __restrict__ flag1, int N) {
    int i = blockIdx.x * blockDim.x + threadIdx.x;
    if (i >= N) return;
    dinv[i] = rsqrtf((float)deg[i] + 1.0f);
    int m = (x[(size_t)i * FIN] == 1.0f) ? 1 : 0;
    mask[i]  = m;
    flag1[i] = m;
}

// ---------------- L1 |= sources of edges into masked targets ----------------
__global__ void k_edge_flag(const int* __restrict__ src, const int* __restrict__ tgt,
                            int E, const int* __restrict__ mask, int* __restrict__ flag1) {
    int e = blockIdx.x * blockDim.x + threadIdx.x;
    if (e < E) {
        if (mask[tgt[e]]) flag1[src[e]] = 1;   // idempotent store, race-free
    }
}

// ------- W1 [K=1024][N=512] f32 -> w1t hi/lo [N=512][K=1024] bf16 (transposed) -------
__global__ void k_cvt_w1(const float* __restrict__ W1, unsigned short* __restrict__ th,
                         unsigned short* __restrict__ tl) {
    int idx = blockIdx.x * blockDim.x + threadIdx.x;
    if (idx >= FIN * FH) return;
    int k = idx / FH, n = idx % FH;   // W1 row-major [k][n]
    float v = W1[idx];
    unsigned short h = f2bf(v);
    unsigned short l = f2bf(v - bf2f(h));
    th[(size_t)n * FIN + k] = h;
    tl[(size_t)n * FIN + k] = l;
}

// ---- h0 = x @ W1 via bf16x3 MFMA: Ah@Bh + Ah@Bl + Al@Bh, f32 accumulate ----
// A: x [M][1024] f32 row-major, split to bf16 hi/lo in-kernel (reg-staged).
// B: w1t hi/lo [512][1024] bf16 (n-major = B^T), staged via global_load_lds.
__global__ __launch_bounds__(256) void k_gemm(const float* __restrict__ Axf,
                                              const unsigned short* __restrict__ Bh,
                                              const unsigned short* __restrict__ Bl,
                                              float* __restrict__ C, int M) {
    __shared__ unsigned short sAh[BM * BK], sAl[BM * BK], sBh[BN * BK], sBl[BN * BK];
    const int tid  = threadIdx.x;
    const int lane = tid & 63;
    const int wid  = tid >> 6;
    const int wm   = wid & 1, wn = wid >> 1;       // 2x2 waves, each owns 64x64
    const int bm   = blockIdx.y * BM, bn = blockIdx.x * BN;
    const int mlim = M - bm;                        // rows valid in this A tile

    const float* pA = Axf + (size_t)bm * FIN;
    const unsigned short* pBh = Bh + (size_t)bn * FIN;
    const unsigned short* pBl = Bl + (size_t)bn * FIN;

    const int s_kc  = (tid & 3) * 8;                // B staging: k-offset (shorts)
    const int a_row = tid >> 3;                     // A staging: row within 32-row group
    const int a_kc  = (tid & 7) * 4;                // A staging: k-offset (floats)

    f32x4 acc[4][4];
    #pragma unroll
    for (int i = 0; i < 4; ++i)
        #pragma unroll
        for (int j = 0; j < 4; ++j)
            #pragma unroll
            for (int r = 0; r < 4; ++r) acc[i][j][r] = 0.f;

    // B tile [128 rows][32 k] row-major; two DMA rounds of 64 rows (wave-linear order:
    // lane l of wave w lands at 1024w + l*16 bytes == row(16w + l>>2), kchunk(l&3). )
#define STAGE_B(S, G)                                                                 \
    __builtin_amdgcn_global_load_lds(                                                 \
        (gvoid*)((G) + (size_t)(tid >> 2) * FIN + k0 + s_kc),                         \
        (lvoid*)((S) + (tid & ~63) * 8), 16, 0, 0);                                   \
    __builtin_amdgcn_global_load_lds(                                                 \
        (gvoid*)((G) + (size_t)(64 + (tid >> 2)) * FIN + k0 + s_kc),                  \
        (lvoid*)((S) + 2048 + (tid & ~63) * 8), 16, 0, 0);

    // fragment offsets (16x16x32: row/col = lane&15, k = (lane>>4)*8 + [0..7])
    const int fa = (wm * 64 + (lane & 15)) * BK + (lane >> 4) * 8;
    const int fb = (wn * 64 + (lane & 15)) * BK + (lane >> 4) * 8;

    for (int k0 = 0; k0 < FIN; k0 += BK) {
        // ---- A: global f32 -> regs (issue first; latency overlaps B DMA) ----
        float4 av[4];
        #pragma unroll
        for (int r = 0; r < 4; ++r) {
            int row = r * 32 + a_row;
            av[r] = make_float4(0.f, 0.f, 0.f, 0.f);
            if (row < mlim)
                av[r] = *(const float4*)&pA[(size_t)row * FIN + k0 + a_kc];
        }
        // ---- B: LDS DMA (safe: all waves passed prev-iter end barrier) ----
        STAGE_B(sBh, pBh)
        STAGE_B(sBl, pBl)
        // ---- A: split + ds_write ----
        #pragma unroll
        for (int r = 0; r < 4; ++r) {
            int row = r * 32 + a_row;
            ushort4 h, l;
            h.x = f2bf(av[r].x); l.x = f2bf(av[r].x - bf2f(h.x));
            h.y = f2bf(av[r].y); l.y = f2bf(av[r].y - bf2f(h.y));
            h.z = f2bf(av[r].z); l.z = f2bf(av[r].z - bf2f(h.z));
            h.w = f2bf(av[r].w); l.w = f2bf(av[r].w - bf2f(h.w));
            *(ushort4*)&sAh[row * BK + a_kc] = h;
            *(ushort4*)&sAl[row * BK + a_kc] = l;
        }
        __syncthreads();   // drains vmcnt (B DMA) + lgkmcnt (A writes)

        short8 ah[4], al[4], bh[4], bl[4];
        #pragma unroll
        for (int i = 0; i < 4; ++i) {
            ah[i] = *(const short8*)&sAh[fa + i * 16 * BK];
            al[i] = *(const short8*)&sAl[fa + i * 16 * BK];
            bh[i] = *(const short8*)&sBh[fb + i * 16 * BK];
            bl[i] = *(const short8*)&sBl[fb + i * 16 * BK];
        }
        #pragma unroll
        for (int i = 0; i < 4; ++i)
            #pragma unroll
            for (int j = 0; j < 4; ++j) {
                acc[i][j] = __builtin_amdgcn_mfma_f32_16x16x32_bf16(ah[i], bh[j], acc[i][j], 0, 0, 0);
                acc[i][j] = __builtin_amdgcn_mfma_f32_16x16x32_bf16(ah[i], bl[j], acc[i][j], 0, 0, 0);
                acc[i][j] = __builtin_amdgcn_mfma_f32_16x16x32_bf16(al[i], bh[j], acc[i][j], 0, 0, 0);
            }
        __syncthreads();   // protect LDS before next iteration's staging
    }
#undef STAGE_B

    // C/D layout (m89-verified): col = lane&15, row = (lane>>4)*4 + reg
    #pragma unroll
    for (int i = 0; i < 4; ++i) {
        int row0 = bm + wm * 64 + i * 16 + (lane >> 4) * 4;
        #pragma unroll
        for (int r = 0; r < 4; ++r) {
            int row = row0 + r;
            if (row < M) {
                float* cp = C + (size_t)row * FH + bn + wn * 64 + (lane & 15);
                #pragma unroll
                for (int j = 0; j < 4; ++j) cp[j * 16] = acc[i][j][r];
            }
        }
    }
}

// ---------------- conv1 aggregation: only into flagged (L1) targets ----------------
__global__ void k_agg1(const int* __restrict__ src, const int* __restrict__ tgt, int E,
                       const int* __restrict__ flag1, const float* __restrict__ dinv,
                       const float* __restrict__ h0, float* __restrict__ agg1) {
    int wave = (blockIdx.x * blockDim.x + threadIdx.x) >> 6;
    int lane = threadIdx.x & 63;
    int nw   = (gridDim.x * blockDim.x) >> 6;
    for (int e = wave; e < E; e += nw) {
        int t = tgt[e];
        if (!flag1[t]) continue;          // wave-uniform skip (~82% of edges)
        int s = src[e];
        float norm = dinv[s] * dinv[t];
        const float4* hv = (const float4*)(h0 + (size_t)s * FH);
        float* at = agg1 + (size_t)t * FH;
        #pragma unroll
        for (int q = 0; q < 2; ++q) {
            float4 v = hv[lane + q * 64];
            int base = (lane + q * 64) * 4;
            atomicAdd(at + base + 0, v.x * norm);
            atomicAdd(at + base + 1, v.y * norm);
            atomicAdd(at + base + 2, v.z * norm);
            atomicAdd(at + base + 3, v.w * norm);
        }
    }
}

// ---- fused: h1 = relu(agg1 + h0*dinv^2 + b1);  s = h1 . W2   (only L1 nodes) ----
__global__ void k_s(const int* __restrict__ flag1, const float* __restrict__ dinv,
                    const float* __restrict__ h0, const float* __restrict__ agg1,
                    const float* __restrict__ b1, const float* __restrict__ W2,
                    float* __restrict__ sval, int N) {
    int wave = (blockIdx.x * blockDim.x + threadIdx.x) >> 6;
    int lane = threadIdx.x & 63;
    int nw   = (gridDim.x * blockDim.x) >> 6;
    const float4* b1v = (const float4*)b1;
    const float4* w2v = (const float4*)W2;
    for (int i = wave; i < N; i += nw) {
        if (!flag1[i]) continue;
        float d2 = dinv[i] * dinv[i];
        const float4* av = (const float4*)(agg1 + (size_t)i * FH);
        const float4* hv = (const float4*)(h0 + (size_t)i * FH);
        float acc = 0.f;
        #pragma unroll
        for (int q = 0; q < 2; ++q) {
            int j = lane + q * 64;
            float4 a = av[j], h = hv[j], bb = b1v[j], w = w2v[j];
            float v0 = fmaxf(a.x + h.x * d2 + bb.x, 0.f);
            float v1 = fmaxf(a.y + h.y * d2 + bb.y, 0.f);
            float v2 = fmaxf(a.z + h.z * d2 + bb.z, 0.f);
            float v3 = fmaxf(a.w + h.w * d2 + bb.w, 0.f);
            acc += v0 * w.x + v1 * w.y + v2 * w.z + v3 * w.w;
        }
        #pragma unroll
        for (int off2 = 32; off2 > 0; off2 >>= 1) acc += __shfl_xor(acc, off2);
        if (lane == 0) sval[i] = acc;
    }
}

// ---------------- conv2 aggregation: only into masked targets (scalar) ----------------
__global__ void k_agg2(const int* __restrict__ src, const int* __restrict__ tgt, int E,
                       const int* __restrict__ mask, const float* __restrict__ dinv,
                       const float* __restrict__ sval, float* __restrict__ outacc) {
    int e = blockIdx.x * blockDim.x + threadIdx.x;
    if (e < E) {
        int t = tgt[e];
        if (mask[t]) {
            int s = src[e];
            atomicAdd(&outacc[t], dinv[s] * dinv[t] * sval[s]);
        }
    }
}

// ---------------- final: out = mask ? agg2 + self + b2 : 0 ----------------
__global__ void k_out(const int* __restrict__ mask, const float* __restrict__ outacc,
                      const float* __restrict__ sval, const float* __restrict__ dinv,
                      const float* __restrict__ b2, float* __restrict__ out, int N) {
    int i = blockIdx.x * blockDim.x + threadIdx.x;
    if (i >= N) return;
    float v = 0.f;
    if (mask[i]) v = outacc[i] + sval[i] * dinv[i] * dinv[i] + b2[0];
    out[i] = v;
}

extern "C" void kernel_launch(void* const* d_in, const int* in_sizes, int n_in,
                              void* d_out, int out_size, void* d_ws, size_t ws_size,
                              hipStream_t stream) {
    const float* x  = (const float*)d_in[0];
    const int*   ei = (const int*)d_in[1];
    const float* W1 = (const float*)d_in[2];
    const float* b1 = (const float*)d_in[3];
    const float* W2 = (const float*)d_in[4];
    const float* b2 = (const float*)d_in[5];

    const int N = in_sizes[0] / FIN;   // 50000
    const int E = in_sizes[1] / 2;     // 400000 (int32: JAX x64 disabled)
    const int* srcA = ei;
    const int* tgtA = ei + E;

    // workspace carve-out (256B aligned). Total ~208 MB.
    char* w = (char*)d_ws;
    size_t off = 0;
    auto alloc = [&](size_t b) { char* p = w + off; off += (b + 255) & ~(size_t)255; return p; };
    int*   deg    = (int*)  alloc((size_t)N * 4);
    float* dinv   = (float*)alloc((size_t)N * 4);
    int*   mask   = (int*)  alloc((size_t)N * 4);
    int*   flag1  = (int*)  alloc((size_t)N * 4);
    float* sval   = (float*)alloc((size_t)N * 4);
    float* outacc = (float*)alloc((size_t)N * 4);
    float* h0     = (float*)alloc((size_t)N * FH * 4);
    float* agg1   = (float*)alloc((size_t)N * FH * 4);
    unsigned short* w1th = (unsigned short*)alloc((size_t)FIN * FH * 2);
    unsigned short* w1tl = (unsigned short*)alloc((size_t)FIN * FH * 2);

    hipMemsetAsync(deg,    0, (size_t)N * 4,      stream);
    hipMemsetAsync(outacc, 0, (size_t)N * 4,      stream);
    hipMemsetAsync(agg1,   0, (size_t)N * FH * 4, stream);

    k_deg<<<(E + 255) / 256, 256, 0, stream>>>(tgtA, E, deg);
    k_node<<<(N + 255) / 256, 256, 0, stream>>>(x, deg, dinv, mask, flag1, N);
    k_edge_flag<<<(E + 255) / 256, 256, 0, stream>>>(srcA, tgtA, E, mask, flag1);
    k_cvt_w1<<<(FIN * FH + 255) / 256, 256, 0, stream>>>(W1, w1th, w1tl);

    // x = n-tile (fast dim): 4 consecutive blocks share one A-panel; per-XCD L2
    // replication of the panel is absorbed by the shared 256MB L3 (x = 205MB fits).
    dim3 gg(FH / BN, (N + BM - 1) / BM);
    k_gemm<<<gg, 256, 0, stream>>>(x, w1th, w1tl, h0, N);

    k_agg1<<<4096, 256, 0, stream>>>(srcA, tgtA, E, flag1, dinv, h0, agg1);
    k_s<<<4096, 256, 0, stream>>>(flag1, dinv, h0, agg1, b1, W2, sval, N);
    k_agg2<<<(E + 255) / 256, 256, 0, stream>>>(srcA, tgtA, E, mask, dinv, sval, outacc);
    k_out<<<(N + 255) / 256, 256, 0, stream>>>(mask, outacc, sval, dinv, b2, (float*)d_out, N);
}

// Round 7
// 558.561 us; speedup vs baseline: 1.7816x; 1.7816x over previous
//
#include <hip/hip_runtime.h>

#define FIN 1024
#define FH  512
#define BM  128
#define BN  128
#define BK  32

typedef __attribute__((ext_vector_type(8))) short short8;
typedef __attribute__((ext_vector_type(4))) float f32x4;
typedef __attribute__((address_space(1))) void gvoid;
typedef __attribute__((address_space(3))) void lvoid;

// ---- bf16 helpers (RNE) ----
static __device__ __forceinline__ unsigned short f2bf(float f) {
    unsigned u = __float_as_uint(f);
    unsigned r = (u + 0x7FFFu + ((u >> 16) & 1u)) >> 16;
    return (unsigned short)r;
}
static __device__ __forceinline__ float bf2f(unsigned short h) {
    return __uint_as_float((unsigned)h << 16);
}

// ---------------- degree: deg[t] = #edges into t ----------------
__global__ void k_deg(const int* __restrict__ tgt, int E, int* __restrict__ deg) {
    int e = blockIdx.x * blockDim.x + threadIdx.x;
    if (e < E) atomicAdd(&deg[tgt[e]], 1);
}

// ---------------- per-node: dinv_sqrt, generator mask, flag init ----------------
__global__ void k_node(const float* __restrict__ x, const int* __restrict__ deg,
                       float* __restrict__ dinv, int* __restrict__ mask,
                       int* __restrict__ flag1, int N) {
    int i = blockIdx.x * blockDim.x + threadIdx.x;
    if (i >= N) return;
    dinv[i] = rsqrtf((float)deg[i] + 1.0f);
    int m = (x[(size_t)i * FIN] == 1.0f) ? 1 : 0;
    mask[i]  = m;
    flag1[i] = m;
}

// ---------------- L1 |= sources of edges into masked targets ----------------
__global__ void k_edge_flag(const int* __restrict__ src, const int* __restrict__ tgt,
                            int E, const int* __restrict__ mask, int* __restrict__ flag1) {
    int e = blockIdx.x * blockDim.x + threadIdx.x;
    if (e < E) {
        if (mask[tgt[e]]) flag1[src[e]] = 1;   // idempotent store, race-free
    }
}

// ---------------- CSR build (scan-free, bucket by active target) ----------------
// acnt[t] = # edges into t, counted only for flagged t
__global__ void k_acnt(const int* __restrict__ tgt, int E, const int* __restrict__ flag1,
                       int* __restrict__ acnt) {
    int e = blockIdx.x * blockDim.x + threadIdx.x;
    if (e < E) {
        int t = tgt[e];
        if (flag1[t]) atomicAdd(&acnt[t], 1);
    }
}

// reserve contiguous ranges per active target; build compact flagged-node list
__global__ void k_base(const int* __restrict__ flag1, const int* __restrict__ acnt,
                       int* __restrict__ aoff, int* __restrict__ list,
                       int* __restrict__ cnts /*[0]=total,[1]=nflag*/, int N) {
    int i = blockIdx.x * blockDim.x + threadIdx.x;
    if (i >= N) return;
    if (flag1[i]) {
        int idx = atomicAdd(&cnts[1], 1);
        list[idx] = i;
    }
    if (acnt[i] > 0) aoff[i] = atomicAdd(&cnts[0], acnt[i]);
}

// scatter sources into their target's reserved range
__global__ void k_fill(const int* __restrict__ src, const int* __restrict__ tgt, int E,
                       const int* __restrict__ flag1, const int* __restrict__ aoff,
                       int* __restrict__ cur, int* __restrict__ csr_src) {
    int e = blockIdx.x * blockDim.x + threadIdx.x;
    if (e < E) {
        int t = tgt[e];
        if (flag1[t]) {
            int pos = aoff[t] + atomicAdd(&cur[t], 1);
            csr_src[pos] = src[e];
        }
    }
}

// ------- W1 [K=1024][N=512] f32 -> w1t hi/lo [N=512][K=1024] bf16 (transposed) -------
__global__ void k_cvt_w1(const float* __restrict__ W1, unsigned short* __restrict__ th,
                         unsigned short* __restrict__ tl) {
    int idx = blockIdx.x * blockDim.x + threadIdx.x;
    if (idx >= FIN * FH) return;
    int k = idx / FH, n = idx % FH;   // W1 row-major [k][n]
    float v = W1[idx];
    unsigned short h = f2bf(v);
    unsigned short l = f2bf(v - bf2f(h));
    th[(size_t)n * FIN + k] = h;
    tl[(size_t)n * FIN + k] = l;
}

// ---- h0 = x @ W1 via bf16x3 MFMA: Ah@Bh + Ah@Bl + Al@Bh, f32 accumulate ----
// A: x [M][1024] f32 row-major, split to bf16 hi/lo in-kernel (reg-staged).
// B: w1t hi/lo [512][1024] bf16 (n-major = B^T), staged via global_load_lds.
__global__ __launch_bounds__(256) void k_gemm(const float* __restrict__ Axf,
                                              const unsigned short* __restrict__ Bh,
                                              const unsigned short* __restrict__ Bl,
                                              float* __restrict__ C, int M) {
    __shared__ unsigned short sAh[BM * BK], sAl[BM * BK], sBh[BN * BK], sBl[BN * BK];
    const int tid  = threadIdx.x;
    const int lane = tid & 63;
    const int wid  = tid >> 6;
    const int wm   = wid & 1, wn = wid >> 1;       // 2x2 waves, each owns 64x64
    const int bm   = blockIdx.y * BM, bn = blockIdx.x * BN;
    const int mlim = M - bm;                        // rows valid in this A tile

    const float* pA = Axf + (size_t)bm * FIN;
    const unsigned short* pBh = Bh + (size_t)bn * FIN;
    const unsigned short* pBl = Bl + (size_t)bn * FIN;

    const int s_kc  = (tid & 3) * 8;                // B staging: k-offset (shorts)
    const int a_row = tid >> 3;                     // A staging: row within 32-row group
    const int a_kc  = (tid & 7) * 4;                // A staging: k-offset (floats)

    f32x4 acc[4][4];
    #pragma unroll
    for (int i = 0; i < 4; ++i)
        #pragma unroll
        for (int j = 0; j < 4; ++j)
            #pragma unroll
            for (int r = 0; r < 4; ++r) acc[i][j][r] = 0.f;

    // B tile [128 rows][32 k] row-major; two DMA rounds of 64 rows (wave-linear order:
    // lane l of wave w lands at 1024w + l*16 bytes == row(16w + l>>2), kchunk(l&3). )
#define STAGE_B(S, G)                                                                 \
    __builtin_amdgcn_global_load_lds(                                                 \
        (gvoid*)((G) + (size_t)(tid >> 2) * FIN + k0 + s_kc),                         \
        (lvoid*)((S) + (tid & ~63) * 8), 16, 0, 0);                                   \
    __builtin_amdgcn_global_load_lds(                                                 \
        (gvoid*)((G) + (size_t)(64 + (tid >> 2)) * FIN + k0 + s_kc),                  \
        (lvoid*)((S) + 2048 + (tid & ~63) * 8), 16, 0, 0);

    // fragment offsets (16x16x32: row/col = lane&15, k = (lane>>4)*8 + [0..7])
    const int fa = (wm * 64 + (lane & 15)) * BK + (lane >> 4) * 8;
    const int fb = (wn * 64 + (lane & 15)) * BK + (lane >> 4) * 8;

    for (int k0 = 0; k0 < FIN; k0 += BK) {
        // ---- A: global f32 -> regs (issue first; latency overlaps B DMA) ----
        float4 av[4];
        #pragma unroll
        for (int r = 0; r < 4; ++r) {
            int row = r * 32 + a_row;
            av[r] = make_float4(0.f, 0.f, 0.f, 0.f);
            if (row < mlim)
                av[r] = *(const float4*)&pA[(size_t)row * FIN + k0 + a_kc];
        }
        // ---- B: LDS DMA (safe: all waves passed prev-iter end barrier) ----
        STAGE_B(sBh, pBh)
        STAGE_B(sBl, pBl)
        // ---- A: split + ds_write ----
        #pragma unroll
        for (int r = 0; r < 4; ++r) {
            int row = r * 32 + a_row;
            ushort4 h, l;
            h.x = f2bf(av[r].x); l.x = f2bf(av[r].x - bf2f(h.x));
            h.y = f2bf(av[r].y); l.y = f2bf(av[r].y - bf2f(h.y));
            h.z = f2bf(av[r].z); l.z = f2bf(av[r].z - bf2f(h.z));
            h.w = f2bf(av[r].w); l.w = f2bf(av[r].w - bf2f(h.w));
            *(ushort4*)&sAh[row * BK + a_kc] = h;
            *(ushort4*)&sAl[row * BK + a_kc] = l;
        }
        __syncthreads();   // drains vmcnt (B DMA) + lgkmcnt (A writes)

        short8 ah[4], al[4], bh[4], bl[4];
        #pragma unroll
        for (int i = 0; i < 4; ++i) {
            ah[i] = *(const short8*)&sAh[fa + i * 16 * BK];
            al[i] = *(const short8*)&sAl[fa + i * 16 * BK];
            bh[i] = *(const short8*)&sBh[fb + i * 16 * BK];
            bl[i] = *(const short8*)&sBl[fb + i * 16 * BK];
        }
        #pragma unroll
        for (int i = 0; i < 4; ++i)
            #pragma unroll
            for (int j = 0; j < 4; ++j) {
                acc[i][j] = __builtin_amdgcn_mfma_f32_16x16x32_bf16(ah[i], bh[j], acc[i][j], 0, 0, 0);
                acc[i][j] = __builtin_amdgcn_mfma_f32_16x16x32_bf16(ah[i], bl[j], acc[i][j], 0, 0, 0);
                acc[i][j] = __builtin_amdgcn_mfma_f32_16x16x32_bf16(al[i], bh[j], acc[i][j], 0, 0, 0);
            }
        __syncthreads();   // protect LDS before next iteration's staging
    }
#undef STAGE_B

    // C/D layout (m89-verified): col = lane&15, row = (lane>>4)*4 + reg
    #pragma unroll
    for (int i = 0; i < 4; ++i) {
        int row0 = bm + wm * 64 + i * 16 + (lane >> 4) * 4;
        #pragma unroll
        for (int r = 0; r < 4; ++r) {
            int row = row0 + r;
            if (row < M) {
                float* cp = C + (size_t)row * FH + bn + wn * 64 + (lane & 15);
                #pragma unroll
                for (int j = 0; j < 4; ++j) cp[j * 16] = acc[i][j][r];
            }
        }
    }
}

// ---- fused conv1-aggregate (CSR gather) + relu + dot(W2): one wave per flagged node ----
// acc_j = sum_{e in CSR[t]} dinv[s]*dinv[t]*h0[s][j];  h1 = relu(acc + h0[t]*dinv^2 + b1)
// sval[t] = h1 . W2   — writes 4B per node, zero atomics.
__global__ void k_gather(const int* __restrict__ list, const int* __restrict__ cnts,
                         const int* __restrict__ aoff, const int* __restrict__ acnt,
                         const int* __restrict__ csr_src,
                         const float* __restrict__ dinv, const float* __restrict__ h0,
                         const float* __restrict__ b1, const float* __restrict__ W2,
                         float* __restrict__ sval) {
    int wave = (blockIdx.x * blockDim.x + threadIdx.x) >> 6;
    int lane = threadIdx.x & 63;
    int nw   = (gridDim.x * blockDim.x) >> 6;
    const int nf = cnts[1];
    const float4* b1v = (const float4*)b1;
    const float4* w2v = (const float4*)W2;
    for (int w = wave; w < nf; w += nw) {
        int t = list[w];
        float dt = dinv[t];
        float4 a0 = make_float4(0.f, 0.f, 0.f, 0.f), a1 = a0;
        int n = acnt[t];
        if (n > 0) {
            int start = aoff[t];
            for (int e = 0; e < n; ++e) {
                int s = csr_src[start + e];
                float norm = dinv[s] * dt;
                const float4* hv = (const float4*)(h0 + (size_t)s * FH);
                float4 v0 = hv[lane], v1 = hv[lane + 64];
                a0.x = fmaf(v0.x, norm, a0.x); a0.y = fmaf(v0.y, norm, a0.y);
                a0.z = fmaf(v0.z, norm, a0.z); a0.w = fmaf(v0.w, norm, a0.w);
                a1.x = fmaf(v1.x, norm, a1.x); a1.y = fmaf(v1.y, norm, a1.y);
                a1.z = fmaf(v1.z, norm, a1.z); a1.w = fmaf(v1.w, norm, a1.w);
            }
        }
        float d2 = dt * dt;
        const float4* ht = (const float4*)(h0 + (size_t)t * FH);
        float4 h0t0 = ht[lane],  h0t1 = ht[lane + 64];
        float4 bb0  = b1v[lane], bb1  = b1v[lane + 64];
        float4 w0   = w2v[lane], w1   = w2v[lane + 64];
        float local =
            fmaxf(fmaf(h0t0.x, d2, a0.x) + bb0.x, 0.f) * w0.x +
            fmaxf(fmaf(h0t0.y, d2, a0.y) + bb0.y, 0.f) * w0.y +
            fmaxf(fmaf(h0t0.z, d2, a0.z) + bb0.z, 0.f) * w0.z +
            fmaxf(fmaf(h0t0.w, d2, a0.w) + bb0.w, 0.f) * w0.w +
            fmaxf(fmaf(h0t1.x, d2, a1.x) + bb1.x, 0.f) * w1.x +
            fmaxf(fmaf(h0t1.y, d2, a1.y) + bb1.y, 0.f) * w1.y +
            fmaxf(fmaf(h0t1.z, d2, a1.z) + bb1.z, 0.f) * w1.z +
            fmaxf(fmaf(h0t1.w, d2, a1.w) + bb1.w, 0.f) * w1.w;
        #pragma unroll
        for (int off2 = 32; off2 > 0; off2 >>= 1) local += __shfl_xor(local, off2);
        if (lane == 0) sval[t] = local;
    }
}

// ---------------- conv2 aggregation: only into masked targets (scalar) ----------------
__global__ void k_agg2(const int* __restrict__ src, const int* __restrict__ tgt, int E,
                       const int* __restrict__ mask, const float* __restrict__ dinv,
                       const float* __restrict__ sval, float* __restrict__ outacc) {
    int e = blockIdx.x * blockDim.x + threadIdx.x;
    if (e < E) {
        int t = tgt[e];
        if (mask[t]) {
            int s = src[e];
            atomicAdd(&outacc[t], dinv[s] * dinv[t] * sval[s]);
        }
    }
}

// ---------------- final: out = mask ? agg2 + self + b2 : 0 ----------------
__global__ void k_out(const int* __restrict__ mask, const float* __restrict__ outacc,
                      const float* __restrict__ sval, const float* __restrict__ dinv,
                      const float* __restrict__ b2, float* __restrict__ out, int N) {
    int i = blockIdx.x * blockDim.x + threadIdx.x;
    if (i >= N) return;
    float v = 0.f;
    if (mask[i]) v = outacc[i] + sval[i] * dinv[i] * dinv[i] + b2[0];
    out[i] = v;
}

extern "C" void kernel_launch(void* const* d_in, const int* in_sizes, int n_in,
                              void* d_out, int out_size, void* d_ws, size_t ws_size,
                              hipStream_t stream) {
    const float* x  = (const float*)d_in[0];
    const int*   ei = (const int*)d_in[1];
    const float* W1 = (const float*)d_in[2];
    const float* b1 = (const float*)d_in[3];
    const float* W2 = (const float*)d_in[4];
    const float* b2 = (const float*)d_in[5];

    const int N = in_sizes[0] / FIN;   // 50000
    const int E = in_sizes[1] / 2;     // 400000 (int32: JAX x64 disabled)
    const int* srcA = ei;
    const int* tgtA = ei + E;

    // workspace carve-out (256B aligned). Total ~107 MB (agg1 buffer deleted).
    char* w = (char*)d_ws;
    size_t off = 0;
    auto alloc = [&](size_t b) { char* p = w + off; off += (b + 255) & ~(size_t)255; return p; };
    // ---- zero-init region (one memset covers deg..cnts incl. padding) ----
    size_t zoff0 = off;
    int*   deg    = (int*)  alloc((size_t)N * 4);
    int*   acnt   = (int*)  alloc((size_t)N * 4);
    int*   cur    = (int*)  alloc((size_t)N * 4);
    float* outacc = (float*)alloc((size_t)N * 4);
    int*   cnts   = (int*)  alloc(256);            // [0]=total, [1]=nflag
    size_t zbytes = off - zoff0;
    // ---- no-init region ----
    float* dinv   = (float*)alloc((size_t)N * 4);
    int*   mask   = (int*)  alloc((size_t)N * 4);
    int*   flag1  = (int*)  alloc((size_t)N * 4);
    float* sval   = (float*)alloc((size_t)N * 4);
    int*   aoff   = (int*)  alloc((size_t)N * 4);
    int*   list   = (int*)  alloc((size_t)N * 4);
    int*   csrs   = (int*)  alloc((size_t)E * 4);
    float* h0     = (float*)alloc((size_t)N * FH * 4);
    unsigned short* w1th = (unsigned short*)alloc((size_t)FIN * FH * 2);
    unsigned short* w1tl = (unsigned short*)alloc((size_t)FIN * FH * 2);

    hipMemsetAsync(w + zoff0, 0, zbytes, stream);

    k_deg<<<(E + 255) / 256, 256, 0, stream>>>(tgtA, E, deg);
    k_node<<<(N + 255) / 256, 256, 0, stream>>>(x, deg, dinv, mask, flag1, N);
    k_edge_flag<<<(E + 255) / 256, 256, 0, stream>>>(srcA, tgtA, E, mask, flag1);

    // CSR over active (flagged-target) edges
    k_acnt<<<(E + 255) / 256, 256, 0, stream>>>(tgtA, E, flag1, acnt);
    k_base<<<(N + 255) / 256, 256, 0, stream>>>(flag1, acnt, aoff, list, cnts, N);
    k_fill<<<(E + 255) / 256, 256, 0, stream>>>(srcA, tgtA, E, flag1, aoff, cur, csrs);

    k_cvt_w1<<<(FIN * FH + 255) / 256, 256, 0, stream>>>(W1, w1th, w1tl);

    // x = n-tile (fast dim): 4 consecutive blocks share one A-panel; per-XCD L2
    // replication of the panel is absorbed by the shared 256MB L3 (x = 205MB fits).
    dim3 gg(FH / BN, (N + BM - 1) / BM);
    k_gemm<<<gg, 256, 0, stream>>>(x, w1th, w1tl, h0, N);

    k_gather<<<2048, 256, 0, stream>>>(list, cnts, aoff, acnt, csrs, dinv, h0, b1, W2, sval);
    k_agg2<<<(E + 255) / 256, 256, 0, stream>>>(srcA, tgtA, E, mask, dinv, sval, outacc);
    k_out<<<(N + 255) / 256, 256, 0, stream>>>(mask, outacc, sval, dinv, b2, (float*)d_out, N);
}

// Round 8
// 553.873 us; speedup vs baseline: 1.7967x; 1.0085x over previous
//
#include <hip/hip_runtime.h>

#define FIN 1024
#define FH  512
#define BM  128
#define BN  128
#define BK  32
#define NT  (FIN / BK)

typedef __attribute__((ext_vector_type(8))) short short8;
typedef __attribute__((ext_vector_type(4))) float f32x4;
typedef __attribute__((address_space(1))) void gvoid;
typedef __attribute__((address_space(3))) void lvoid;

// ---- bf16 helpers (RNE) ----
static __device__ __forceinline__ unsigned short f2bf(float f) {
    unsigned u = __float_as_uint(f);
    unsigned r = (u + 0x7FFFu + ((u >> 16) & 1u)) >> 16;
    return (unsigned short)r;
}
static __device__ __forceinline__ float bf2f(unsigned short h) {
    return __uint_as_float((unsigned)h << 16);
}

// ---------------- per-node: generator mask + flag init (no deg dependency) ----------------
__global__ void k_mask(const float* __restrict__ x, int* __restrict__ mask,
                       int* __restrict__ flag1, int N) {
    int i = blockIdx.x * blockDim.x + threadIdx.x;
    if (i >= N) return;
    int m = (x[(size_t)i * FIN] == 1.0f) ? 1 : 0;
    mask[i]  = m;
    flag1[i] = m;
}

// ---------------- L1 |= sources of edges into masked targets ----------------
__global__ void k_edge_flag(const int* __restrict__ src, const int* __restrict__ tgt,
                            int E, const int* __restrict__ mask, int* __restrict__ flag1) {
    int e = blockIdx.x * blockDim.x + threadIdx.x;
    if (e < E) {
        if (mask[tgt[e]]) flag1[src[e]] = 1;   // idempotent store, race-free
    }
}

// ---------------- fused edge pass: deg (all targets) + acnt (flagged targets) ----------------
__global__ void k_deg_acnt(const int* __restrict__ tgt, int E, const int* __restrict__ flag1,
                           int* __restrict__ deg, int* __restrict__ acnt) {
    int e = blockIdx.x * blockDim.x + threadIdx.x;
    if (e < E) {
        int t = tgt[e];
        atomicAdd(&deg[t], 1);
        if (flag1[t]) atomicAdd(&acnt[t], 1);
    }
}

// ---- per-node: dinv; reserve CSR ranges; compact flagged-node list ----
__global__ void k_base(const int* __restrict__ flag1, const int* __restrict__ deg,
                       const int* __restrict__ acnt, float* __restrict__ dinv,
                       int* __restrict__ aoff, int* __restrict__ list,
                       int* __restrict__ cnts /*[0]=total,[1]=nflag*/, int N) {
    int i = blockIdx.x * blockDim.x + threadIdx.x;
    if (i >= N) return;
    dinv[i] = rsqrtf((float)deg[i] + 1.0f);
    if (flag1[i]) {
        int idx = atomicAdd(&cnts[1], 1);
        list[idx] = i;
    }
    if (acnt[i] > 0) aoff[i] = atomicAdd(&cnts[0], acnt[i]);
}

// scatter sources into their target's reserved range
__global__ void k_fill(const int* __restrict__ src, const int* __restrict__ tgt, int E,
                       const int* __restrict__ flag1, const int* __restrict__ aoff,
                       int* __restrict__ cur, int* __restrict__ csr_src) {
    int e = blockIdx.x * blockDim.x + threadIdx.x;
    if (e < E) {
        int t = tgt[e];
        if (flag1[t]) {
            int pos = aoff[t] + atomicAdd(&cur[t], 1);
            csr_src[pos] = src[e];
        }
    }
}

// ------- W1 [K=1024][N=512] f32 -> w1t hi/lo [N=512][K=1024] bf16, LDS-tiled transpose -------
__global__ __launch_bounds__(256) void k_cvt_w1(const float* __restrict__ W1,
                                                unsigned short* __restrict__ th,
                                                unsigned short* __restrict__ tl) {
    __shared__ float tile[32][33];
    const int nb = blockIdx.x * 32;   // n block (16 blocks)
    const int kb = blockIdx.y * 32;   // k block (32 blocks)
    const int tx = threadIdx.x & 31, ty = threadIdx.x >> 5;   // 32x8
    #pragma unroll
    for (int r = 0; r < 4; ++r)       // coalesced 128B row reads
        tile[ty + r * 8][tx] = W1[(size_t)(kb + ty + r * 8) * FH + nb + tx];
    __syncthreads();
    #pragma unroll
    for (int r = 0; r < 4; ++r) {     // coalesced 64B row writes
        int n = nb + ty + r * 8;
        float v = tile[tx][ty + r * 8];
        unsigned short h = f2bf(v);
        unsigned short l = f2bf(v - bf2f(h));
        th[(size_t)n * FIN + kb + tx] = h;
        tl[(size_t)n * FIN + kb + tx] = l;
    }
}

// ---- h0 = x @ W1 via bf16x3 MFMA, double-buffered LDS (T3-minimum 2-phase) ----
// A: x [M][1024] f32 row-major, split to bf16 hi/lo in-kernel (reg-staged).
// B: w1t hi/lo [512][1024] bf16 (n-major = B^T), staged via global_load_lds.
__global__ __launch_bounds__(256) void k_gemm(const float* __restrict__ Axf,
                                              const unsigned short* __restrict__ Bh,
                                              const unsigned short* __restrict__ Bl,
                                              float* __restrict__ C, int M) {
    __shared__ unsigned short sAh[2][BM * BK], sAl[2][BM * BK],
                              sBh[2][BN * BK], sBl[2][BN * BK];   // 64 KB total
    const int tid  = threadIdx.x;
    const int lane = tid & 63;
    const int wid  = tid >> 6;
    const int wm   = wid & 1, wn = wid >> 1;       // 2x2 waves, each owns 64x64
    const int bm   = blockIdx.y * BM, bn = blockIdx.x * BN;
    const int mlim = M - bm;

    const float* pA = Axf + (size_t)bm * FIN;
    const unsigned short* pBh = Bh + (size_t)bn * FIN;
    const unsigned short* pBl = Bl + (size_t)bn * FIN;

    const int s_kc  = (tid & 3) * 8;                // B staging: k-offset (shorts)
    const int a_row = tid >> 3;                     // A staging: row in 32-row group
    const int a_kc  = (tid & 7) * 4;                // A staging: k-offset (floats)

    f32x4 acc[4][4];
    #pragma unroll
    for (int i = 0; i < 4; ++i)
        #pragma unroll
        for (int j = 0; j < 4; ++j)
            #pragma unroll
            for (int r = 0; r < 4; ++r) acc[i][j][r] = 0.f;

    // B tile [128 rows][32 k]; wave-linear DMA: lane l of wave w -> row(16w+l>>2), kchunk(l&3)
#define STAGE_B(S, G, K0)                                                             \
    __builtin_amdgcn_global_load_lds(                                                 \
        (gvoid*)((G) + (size_t)(tid >> 2) * FIN + (K0) + s_kc),                       \
        (lvoid*)((S) + (tid & ~63) * 8), 16, 0, 0);                                   \
    __builtin_amdgcn_global_load_lds(                                                 \
        (gvoid*)((G) + (size_t)(64 + (tid >> 2)) * FIN + (K0) + s_kc),                \
        (lvoid*)((S) + 2048 + (tid & ~63) * 8), 16, 0, 0);

#define LOAD_A(AV, K0)                                                                \
    _Pragma("unroll")                                                                 \
    for (int r = 0; r < 4; ++r) {                                                     \
        int row_ = r * 32 + a_row;                                                    \
        AV[r] = make_float4(0.f, 0.f, 0.f, 0.f);                                      \
        if (row_ < mlim)                                                              \
            AV[r] = *(const float4*)&pA[(size_t)row_ * FIN + (K0) + a_kc];            \
    }

#define SPLIT_A(SH, SL, AV)                                                           \
    _Pragma("unroll")                                                                 \
    for (int r = 0; r < 4; ++r) {                                                     \
        int row_ = r * 32 + a_row;                                                    \
        ushort4 h_, l_;                                                               \
        h_.x = f2bf(AV[r].x); l_.x = f2bf(AV[r].x - bf2f(h_.x));                      \
        h_.y = f2bf(AV[r].y); l_.y = f2bf(AV[r].y - bf2f(h_.y));                      \
        h_.z = f2bf(AV[r].z); l_.z = f2bf(AV[r].z - bf2f(h_.z));                      \
        h_.w = f2bf(AV[r].w); l_.w = f2bf(AV[r].w - bf2f(h_.w));                      \
        *(ushort4*)&(SH)[row_ * BK + a_kc] = h_;                                      \
        *(ushort4*)&(SL)[row_ * BK + a_kc] = l_;                                      \
    }

    // fragment offsets (16x16x32: row/col = lane&15, k = (lane>>4)*8 + [0..7])
    const int fa = (wm * 64 + (lane & 15)) * BK + (lane >> 4) * 8;
    const int fb = (wn * 64 + (lane & 15)) * BK + (lane >> 4) * 8;

    // ---- prologue: stage tile 0 into buf 0 ----
    float4 av[4];
    LOAD_A(av, 0)
    STAGE_B(sBh[0], pBh, 0)
    STAGE_B(sBl[0], pBl, 0)
    SPLIT_A(sAh[0], sAl[0], av)
    __syncthreads();

    for (int t = 0; t < NT; ++t) {
        const int cur = t & 1, nxt = cur ^ 1;
        const int k1 = (t + 1) * BK;
        if (t + 1 < NT) {
            LOAD_A(av, k1)                   // issue early: latency under MFMA
            STAGE_B(sBh[nxt], pBh, k1)
            STAGE_B(sBl[nxt], pBl, k1)
        }
        short8 ah[4], al[4], bh[4], bl[4];
        #pragma unroll
        for (int i = 0; i < 4; ++i) {
            ah[i] = *(const short8*)&sAh[cur][fa + i * 16 * BK];
            al[i] = *(const short8*)&sAl[cur][fa + i * 16 * BK];
            bh[i] = *(const short8*)&sBh[cur][fb + i * 16 * BK];
            bl[i] = *(const short8*)&sBl[cur][fb + i * 16 * BK];
        }
        #pragma unroll
        for (int i = 0; i < 4; ++i)
            #pragma unroll
            for (int j = 0; j < 4; ++j) {
                acc[i][j] = __builtin_amdgcn_mfma_f32_16x16x32_bf16(ah[i], bh[j], acc[i][j], 0, 0, 0);
                acc[i][j] = __builtin_amdgcn_mfma_f32_16x16x32_bf16(ah[i], bl[j], acc[i][j], 0, 0, 0);
                acc[i][j] = __builtin_amdgcn_mfma_f32_16x16x32_bf16(al[i], bh[j], acc[i][j], 0, 0, 0);
            }
        if (t + 1 < NT)
            SPLIT_A(sAh[nxt], sAl[nxt], av)   // waits on av loads here (post-MFMA)
        __syncthreads();   // one drain per tile: B-DMA(t+1) + A-writes done; cur released
    }
#undef STAGE_B
#undef LOAD_A
#undef SPLIT_A

    // C/D layout (m89-verified): col = lane&15, row = (lane>>4)*4 + reg
    #pragma unroll
    for (int i = 0; i < 4; ++i) {
        int row0 = bm + wm * 64 + i * 16 + (lane >> 4) * 4;
        #pragma unroll
        for (int r = 0; r < 4; ++r) {
            int row = row0 + r;
            if (row < M) {
                float* cp = C + (size_t)row * FH + bn + wn * 64 + (lane & 15);
                #pragma unroll
                for (int j = 0; j < 4; ++j) cp[j * 16] = acc[i][j][r];
            }
        }
    }
}

// ---- fused conv1-aggregate (CSR gather) + relu + dot(W2): one wave per flagged node ----
__global__ void k_gather(const int* __restrict__ list, const int* __restrict__ cnts,
                         const int* __restrict__ aoff, const int* __restrict__ acnt,
                         const int* __restrict__ csr_src,
                         const float* __restrict__ dinv, const float* __restrict__ h0,
                         const float* __restrict__ b1, const float* __restrict__ W2,
                         float* __restrict__ sval) {
    int wave = (blockIdx.x * blockDim.x + threadIdx.x) >> 6;
    int lane = threadIdx.x & 63;
    int nw   = (gridDim.x * blockDim.x) >> 6;
    const int nf = cnts[1];
    const float4* b1v = (const float4*)b1;
    const float4* w2v = (const float4*)W2;
    for (int w = wave; w < nf; w += nw) {
        int t = list[w];
        float dt = dinv[t];
        float4 a0 = make_float4(0.f, 0.f, 0.f, 0.f), a1 = a0;
        int n = acnt[t];
        if (n > 0) {
            int start = aoff[t];
            for (int e = 0; e < n; ++e) {
                int s = csr_src[start + e];
                float norm = dinv[s] * dt;
                const float4* hv = (const float4*)(h0 + (size_t)s * FH);
                float4 v0 = hv[lane], v1 = hv[lane + 64];
                a0.x = fmaf(v0.x, norm, a0.x); a0.y = fmaf(v0.y, norm, a0.y);
                a0.z = fmaf(v0.z, norm, a0.z); a0.w = fmaf(v0.w, norm, a0.w);
                a1.x = fmaf(v1.x, norm, a1.x); a1.y = fmaf(v1.y, norm, a1.y);
                a1.z = fmaf(v1.z, norm, a1.z); a1.w = fmaf(v1.w, norm, a1.w);
            }
        }
        float d2 = dt * dt;
        const float4* ht = (const float4*)(h0 + (size_t)t * FH);
        float4 h0t0 = ht[lane],  h0t1 = ht[lane + 64];
        float4 bb0  = b1v[lane], bb1  = b1v[lane + 64];
        float4 w0   = w2v[lane], w1   = w2v[lane + 64];
        float local =
            fmaxf(fmaf(h0t0.x, d2, a0.x) + bb0.x, 0.f) * w0.x +
            fmaxf(fmaf(h0t0.y, d2, a0.y) + bb0.y, 0.f) * w0.y +
            fmaxf(fmaf(h0t0.z, d2, a0.z) + bb0.z, 0.f) * w0.z +
            fmaxf(fmaf(h0t0.w, d2, a0.w) + bb0.w, 0.f) * w0.w +
            fmaxf(fmaf(h0t1.x, d2, a1.x) + bb1.x, 0.f) * w1.x +
            fmaxf(fmaf(h0t1.y, d2, a1.y) + bb1.y, 0.f) * w1.y +
            fmaxf(fmaf(h0t1.z, d2, a1.z) + bb1.z, 0.f) * w1.z +
            fmaxf(fmaf(h0t1.w, d2, a1.w) + bb1.w, 0.f) * w1.w;
        #pragma unroll
        for (int off2 = 32; off2 > 0; off2 >>= 1) local += __shfl_xor(local, off2);
        if (lane == 0) sval[t] = local;
    }
}

// ---------------- conv2 aggregation: only into masked targets (scalar) ----------------
__global__ void k_agg2(const int* __restrict__ src, const int* __restrict__ tgt, int E,
                       const int* __restrict__ mask, const float* __restrict__ dinv,
                       const float* __restrict__ sval, float* __restrict__ outacc) {
    int e = blockIdx.x * blockDim.x + threadIdx.x;
    if (e < E) {
        int t = tgt[e];
        if (mask[t]) {
            int s = src[e];
            atomicAdd(&outacc[t], dinv[s] * dinv[t] * sval[s]);
        }
    }
}

// ---------------- final: out = mask ? agg2 + self + b2 : 0 ----------------
__global__ void k_out(const int* __restrict__ mask, const float* __restrict__ outacc,
                      const float* __restrict__ sval, const float* __restrict__ dinv,
                      const float* __restrict__ b2, float* __restrict__ out, int N) {
    int i = blockIdx.x * blockDim.x + threadIdx.x;
    if (i >= N) return;
    float v = 0.f;
    if (mask[i]) v = outacc[i] + sval[i] * dinv[i] * dinv[i] + b2[0];
    out[i] = v;
}

extern "C" void kernel_launch(void* const* d_in, const int* in_sizes, int n_in,
                              void* d_out, int out_size, void* d_ws, size_t ws_size,
                              hipStream_t stream) {
    const float* x  = (const float*)d_in[0];
    const int*   ei = (const int*)d_in[1];
    const float* W1 = (const float*)d_in[2];
    const float* b1 = (const float*)d_in[3];
    const float* W2 = (const float*)d_in[4];
    const float* b2 = (const float*)d_in[5];

    const int N = in_sizes[0] / FIN;   // 50000
    const int E = in_sizes[1] / 2;     // 400000 (int32: JAX x64 disabled)
    const int* srcA = ei;
    const int* tgtA = ei + E;

    // workspace carve-out (256B aligned). Total ~107 MB.
    char* w = (char*)d_ws;
    size_t off = 0;
    auto alloc = [&](size_t b) { char* p = w + off; off += (b + 255) & ~(size_t)255; return p; };
    // ---- zero-init region (one memset covers deg..cnts incl. padding) ----
    size_t zoff0 = off;
    int*   deg    = (int*)  alloc((size_t)N * 4);
    int*   acnt   = (int*)  alloc((size_t)N * 4);
    int*   cur    = (int*)  alloc((size_t)N * 4);
    float* outacc = (float*)alloc((size_t)N * 4);
    int*   cnts   = (int*)  alloc(256);            // [0]=total, [1]=nflag
    size_t zbytes = off - zoff0;
    // ---- no-init region ----
    float* dinv   = (float*)alloc((size_t)N * 4);
    int*   mask   = (int*)  alloc((size_t)N * 4);
    int*   flag1  = (int*)  alloc((size_t)N * 4);
    float* sval   = (float*)alloc((size_t)N * 4);
    int*   aoff   = (int*)  alloc((size_t)N * 4);
    int*   list   = (int*)  alloc((size_t)N * 4);
    int*   csrs   = (int*)  alloc((size_t)E * 4);
    float* h0     = (float*)alloc((size_t)N * FH * 4);
    unsigned short* w1th = (unsigned short*)alloc((size_t)FIN * FH * 2);
    unsigned short* w1tl = (unsigned short*)alloc((size_t)FIN * FH * 2);

    hipMemsetAsync(w + zoff0, 0, zbytes, stream);

    k_mask<<<(N + 255) / 256, 256, 0, stream>>>(x, mask, flag1, N);
    k_edge_flag<<<(E + 255) / 256, 256, 0, stream>>>(srcA, tgtA, E, mask, flag1);
    k_deg_acnt<<<(E + 255) / 256, 256, 0, stream>>>(tgtA, E, flag1, deg, acnt);
    k_base<<<(N + 255) / 256, 256, 0, stream>>>(flag1, deg, acnt, dinv, aoff, list, cnts, N);
    k_fill<<<(E + 255) / 256, 256, 0, stream>>>(srcA, tgtA, E, flag1, aoff, cur, csrs);

    dim3 gw(FH / 32, FIN / 32);
    k_cvt_w1<<<gw, 256, 0, stream>>>(W1, w1th, w1tl);

    // x = n-tile (fast dim): consecutive blocks share one A-panel (L2/L3 reuse)
    dim3 gg(FH / BN, (N + BM - 1) / BM);
    k_gemm<<<gg, 256, 0, stream>>>(x, w1th, w1tl, h0, N);

    k_gather<<<2048, 256, 0, stream>>>(list, cnts, aoff, acnt, csrs, dinv, h0, b1, W2, sval);
    k_agg2<<<(E + 255) / 256, 256, 0, stream>>>(srcA, tgtA, E, mask, dinv, sval, outacc);
    k_out<<<(N + 255) / 256, 256, 0, stream>>>(mask, outacc, sval, dinv, b2, (float*)d_out, N);
}